// Round 13
// baseline (117.414 us; speedup 1.0000x reference)
//
#include <hip/hip_runtime.h>

#define T_LEN 50

typedef __fp16 fp16x8 __attribute__((ext_vector_type(8)));
typedef float f32x16 __attribute__((ext_vector_type(16)));
typedef unsigned int uint4v __attribute__((ext_vector_type(4)));

__device__ __forceinline__ float EXP2(float x){ return __builtin_amdgcn_exp2f(x); }
__device__ __forceinline__ float RCP(float x){ return __builtin_amdgcn_rcpf(x); }
// pack two f32 -> two f16 in one u32 (v_cvt_pkrtz_f16_f32); low word = first arg
__device__ __forceinline__ unsigned PKU(float a, float b){
    return __builtin_bit_cast(unsigned, __builtin_amdgcn_cvt_pkrtz(a, b));
}

// LSTM pointwise stage for one (layer, unit, element). Gates pre-scaled:
// i,f,o by S1=-log2e; g by S2=-2log2e (folded into weights+bias).
// c' = [c*B*C + (1-q)*A] * rcp(A*B*C); h = (1-u)*rcp((1+s)(1+u)), u=2^min(c*S2,96)
__device__ __forceinline__ void act(float gi, float gf, float gg, float go,
                                    float& c, float& h){
    const float S2 = -2.8853900817779268f;
    const float p = EXP2(gi);
    const float r = EXP2(gf);
    const float q = EXP2(gg);
    const float s = EXP2(go);
    const float A  = 1.0f + r;
    const float BC = (1.0f + p) * (1.0f + q);
    const float num = fmaf(c, BC, (1.0f - q) * A);
    c = num * RCP(A * BC);
    const float u = EXP2(fminf(c * S2, 96.0f));
    h = (1.0f - u) * RCP((1.0f + s) * (1.0f + u));
}

// Wave tile: 32 batch elements. One mfma_f32_32x32x16_f16 per time step computes
// L0 gates(t) (A-rows 0-15: q=0..3) and L1 gates(t-1) (A-rows 16-31: q=4..7),
// with B = [x(t) k0-1; h0(t-1) k2-5; h1(t-2) k6-9; 0 k10-15], bias in C.
// A row m=4q+tg; D/C: col=lane&31=e, row=(r&3)+8*(r>>2)+4*(lane>>5) => lane(h,e)
// holds quads q={h,2+h} (L0) and {4+h,6+h} (L1): 4 lane-local acts.
// A: lane supplies A[m=lane&31][k=8*(lane>>5)+i]; B: B[k=8*(lane>>5)+i][n=lane&31].
__global__ __launch_bounds__(256, 4) void lstm_mfma32(
    const float* __restrict__ x,
    const float* __restrict__ Wih0, const float* __restrict__ Whh0,
    const float* __restrict__ bih0, const float* __restrict__ bhh0,
    const float* __restrict__ Wih1, const float* __restrict__ Whh1,
    const float* __restrict__ bih1, const float* __restrict__ bhh1,
    const float* __restrict__ Wout, const float* __restrict__ bout,
    float* __restrict__ out, int B)
{
    __shared__ float2 wout_s[T_LEN*2];   // [t][h] = (Wout[t*4+h], Wout[t*4+h+2])
    const int tid = threadIdx.x;
    if (tid < T_LEN*2){
        const int t = tid >> 1, hh = tid & 1;
        wout_s[tid] = make_float2(Wout[t*4+hh], Wout[t*4+hh+2]);
    }
    __syncthreads();

    const int lane = tid & 63;
    const int e = lane & 31;          // element column
    const int h = lane >> 5;          // half: owns units {h, 2+h} per layer
    const int wave = (blockIdx.x*256 + tid) >> 6;
    const int E0 = wave * 32;
    if (E0 >= B) return;

    const float S1 = -1.4426950408889634f;
    const float S2 = -2.8853900817779268f;

    // ---- A fragment: lane supplies row mA=e, k=8h+0..7 ----
    const int qA = e >> 2, tA = e & 3;
    const float sA = (tA == 2) ? S2 : S1;
    uint4v au;
#pragma unroll
    for (int p = 0; p < 4; ++p){
        float vv[2];
#pragma unroll
        for (int z = 0; z < 2; ++z){
            const int k = 8*h + 2*p + z;
            float v = 0.f;
            if (qA < 4){                          // L0 rows: x(k0-1), h0(k2-5)
                const int r = tA*4 + qA;
                if (k < 2)      v = Wih0[r*2 + k];
                else if (k < 6) v = Whh0[r*4 + (k-2)];
            } else {                              // L1 rows: h0(k2-5), h1(k6-9)
                const int r = tA*4 + (qA-4);
                if (k >= 2 && k < 6)       v = Wih1[r*4 + (k-2)];
                else if (k >= 6 && k < 10) v = Whh1[r*4 + (k-6)];
            }
            vv[z] = v * sA;
        }
        au[p] = PKU(vv[0], vv[1]);
    }
    const fp16x8 Afrag = __builtin_bit_cast(fp16x8, au);

    // ---- bias as C operand (loop-invariant) ----
    f32x16 biasC;
#pragma unroll
    for (int r = 0; r < 16; ++r){
        const int m = (r&3) + 8*(r>>2) + 4*h;
        const int q = m >> 2, tg = m & 3;
        const float st = (tg == 2) ? S2 : S1;
        if (q < 4){ const int rr = tg*4 + q;      biasC[r] = (bih0[rr]+bhh0[rr])*st; }
        else      { const int rr = tg*4 + (q-4);  biasC[r] = (bih1[rr]+bhh1[rr])*st; }
    }

    float c0l=0.f, c0h=0.f, c1l=0.f, c1h=0.f, acc=0.f;
    unsigned pk_h0_01=0u, pk_h0_23=0u, pk_h1_01=0u, pk_h1_23=0u;

    const float* xp = x + (size_t)(E0 + e) * (T_LEN*2);

    // ---- prologue t=0: L0 act only ----
    {
        const float2 xv = *reinterpret_cast<const float2*>(xp);
        const unsigned ux = PKU(xv.x, xv.y);
        uint4v bu; bu[0] = h ? 0u : ux; bu[1] = 0u; bu[2] = 0u; bu[3] = 0u;
        const f32x16 d = __builtin_amdgcn_mfma_f32_32x32x16_f16(
            Afrag, __builtin_bit_cast(fp16x8, bu), biasC, 0, 0, 0);
        float h0l, h0h;
        act(d[0],d[1],d[2],d[3], c0l, h0l);
        act(d[4],d[5],d[6],d[7], c0h, h0h);
        const float r0l = __shfl_xor(h0l, 32, 64);
        const float r0h = __shfl_xor(h0h, 32, 64);
        pk_h0_01 = PKU(h0l, r0l);     // (u0,u1) valid on half0
        pk_h0_23 = PKU(h0h, r0h);     // (u2,u3) valid on half0
    }

    // ---- main: iter t computes L0(t) and L1(t-1) ----
    for (int t = 1; t < T_LEN; ++t){
        const float2 xv = *reinterpret_cast<const float2*>(xp + t*2);
        const unsigned ux = PKU(xv.x, xv.y);
        uint4v bu;
        bu[0] = h ? pk_h1_23 : ux;    // half0: k0-1=x; half1: k8-9=(h1_2,h1_3)
        bu[1] = pk_h0_01;             // half0: k2-3; half1: k10-11 (A=0, don't care)
        bu[2] = pk_h0_23;             // half0: k4-5
        bu[3] = pk_h1_01;             // half0: k6-7
        const f32x16 d = __builtin_amdgcn_mfma_f32_32x32x16_f16(
            Afrag, __builtin_bit_cast(fp16x8, bu), biasC, 0, 0, 0);
        float h0l,h0h,h1l,h1h;
        act(d[0], d[1], d[2], d[3],  c0l, h0l);    // L0 unit h
        act(d[4], d[5], d[6], d[7],  c0h, h0h);    // L0 unit 2+h
        act(d[8], d[9], d[10],d[11], c1l, h1l);    // L1 unit h    (time t-1)
        act(d[12],d[13],d[14],d[15], c1h, h1h);    // L1 unit 2+h  (time t-1)
        const float2 wo = wout_s[(t-1)*2 + h];
        acc = fmaf(h1l, wo.x, fmaf(h1h, wo.y, acc));
        const float r0l = __shfl_xor(h0l,32,64), r0h = __shfl_xor(h0h,32,64);
        const float r1l = __shfl_xor(h1l,32,64), r1h = __shfl_xor(h1h,32,64);
        pk_h0_01 = PKU(h0l, r0l);
        pk_h0_23 = PKU(h0h, r0h);
        pk_h1_01 = PKU(h1l, r1l);     // (u0,u1) for half0's k6-7
        pk_h1_23 = PKU(r1h, h1h);     // (u2,u3) for half1's k8-9
    }

    // ---- epilogue: L1 at t=49 ----
    {
        uint4v bu;
        bu[0] = h ? pk_h1_23 : 0u;
        bu[1] = pk_h0_01; bu[2] = pk_h0_23; bu[3] = pk_h1_01;
        const f32x16 d = __builtin_amdgcn_mfma_f32_32x32x16_f16(
            Afrag, __builtin_bit_cast(fp16x8, bu), biasC, 0, 0, 0);
        float h1l, h1h;
        act(d[8], d[9], d[10],d[11], c1l, h1l);
        act(d[12],d[13],d[14],d[15], c1h, h1h);
        const float2 wo = wout_s[49*2 + h];
        acc = fmaf(h1l, wo.x, fmaf(h1h, wo.y, acc));
    }

    acc += __shfl_xor(acc, 32, 64);   // sum unit-halves
    if (h == 0){
        const float z = acc + bout[0];
        out[E0 + e] = RCP(1.0f + EXP2(z * S1));   // sigmoid
    }
}

extern "C" void kernel_launch(void* const* d_in, const int* in_sizes, int n_in,
                              void* d_out, int out_size, void* d_ws, size_t ws_size,
                              hipStream_t stream)
{
    const float* x    = (const float*)d_in[0];
    const float* Wih0 = (const float*)d_in[1];
    const float* Whh0 = (const float*)d_in[2];
    const float* bih0 = (const float*)d_in[3];
    const float* bhh0 = (const float*)d_in[4];
    const float* Wih1 = (const float*)d_in[5];
    const float* Whh1 = (const float*)d_in[6];
    const float* bih1 = (const float*)d_in[7];
    const float* bhh1 = (const float*)d_in[8];
    const float* Wout = (const float*)d_in[9];
    const float* bout = (const float*)d_in[10];
    float* out = (float*)d_out;

    const int B = in_sizes[0] / (T_LEN*2);
    const int waves = (B + 31) / 32;
    const int blocks = (waves + 3) / 4;       // 4 waves per 256-thread block
    lstm_mfma32<<<blocks, 256, 0, stream>>>(x, Wih0, Whh0, bih0, bhh0,
                                            Wih1, Whh1, bih1, bhh1,
                                            Wout, bout, out, B);
}

// Round 14
// 97.544 us; speedup vs baseline: 1.2037x; 1.2037x over previous
//
#include <hip/hip_runtime.h>

#define T_LEN 50
#define RS 50   // LDS floats per element chunk-row (24 steps = 48 floats + 2 pad)

typedef __fp16 fp16x8 __attribute__((ext_vector_type(8)));
typedef float f32x16 __attribute__((ext_vector_type(16)));
typedef unsigned int uint4v __attribute__((ext_vector_type(4)));

__device__ __forceinline__ float EXP2(float x){ return __builtin_amdgcn_exp2f(x); }
__device__ __forceinline__ float RCP(float x){ return __builtin_amdgcn_rcpf(x); }
__device__ __forceinline__ unsigned PKU(float a, float b){
    return __builtin_bit_cast(unsigned, __builtin_amdgcn_cvt_pkrtz(a, b));
}

// LSTM pointwise stage for one (layer, unit, element). Gates pre-scaled:
// i,f,o by S1=-log2e; g by S2=-2log2e (folded into weights+bias).
__device__ __forceinline__ void act(float gi, float gf, float gg, float go,
                                    float& c, float& h){
    const float S2 = -2.8853900817779268f;
    const float p = EXP2(gi);
    const float r = EXP2(gf);
    const float q = EXP2(gg);
    const float s = EXP2(go);
    const float A  = 1.0f + r;
    const float BC = (1.0f + p) * (1.0f + q);
    const float num = fmaf(c, BC, (1.0f - q) * A);
    c = num * RCP(A * BC);
    const float u = EXP2(fminf(c * S2, 96.0f));
    h = (1.0f - u) * RCP((1.0f + s) * (1.0f + u));
}

// Wave tile: 32 elements. One mfma_f32_32x32x16_f16 per step: L0 gates(t) rows 0-15,
// L1 gates(t-1) rows 16-31. B = [x(t) k0-1 | h0 k2-5 | h1 k6-9 | 0]. Bias in C.
// x is staged through wave-private LDS (coalesced 24-step chunks, reg-prefetched).
__global__ __launch_bounds__(256, 6) void lstm_mfma32(
    const float* __restrict__ x,
    const float* __restrict__ Wih0, const float* __restrict__ Whh0,
    const float* __restrict__ bih0, const float* __restrict__ bhh0,
    const float* __restrict__ Wih1, const float* __restrict__ Whh1,
    const float* __restrict__ bih1, const float* __restrict__ bhh1,
    const float* __restrict__ Wout, const float* __restrict__ bout,
    float* __restrict__ out, int B)
{
    __shared__ float lds[200 + 4*32*RS];   // wout (200 floats) + 4 wave regions
    const int tid = threadIdx.x;
    float2* wout_s = reinterpret_cast<float2*>(lds);   // [t][h]=(W[t*4+h],W[t*4+h+2])
    if (tid < T_LEN*2){
        const int t = tid >> 1, hh = tid & 1;
        wout_s[tid] = make_float2(Wout[t*4+hh], Wout[t*4+hh+2]);
    }
    __syncthreads();

    const int lane = tid & 63;
    const int e = lane & 31;          // element column
    const int h = lane >> 5;          // half: owns units {h, 2+h} per layer
    const int wslot = tid >> 6;
    const int wave = (blockIdx.x*256 + tid) >> 6;
    const int E0 = wave * 32;
    if (E0 >= B) return;

    float* xr = lds + 200 + wslot * (32*RS);   // wave-private x stage

    const float S1 = -1.4426950408889634f;
    const float S2 = -2.8853900817779268f;

    // ---- A fragment: lane supplies row mA=e, k=8h+0..7 ----
    const int qA = e >> 2, tA = e & 3;
    const float sA = (tA == 2) ? S2 : S1;
    uint4v au;
#pragma unroll
    for (int p = 0; p < 4; ++p){
        float vv[2];
#pragma unroll
        for (int z = 0; z < 2; ++z){
            const int k = 8*h + 2*p + z;
            float v = 0.f;
            if (qA < 4){                          // L0 rows: x(k0-1), h0(k2-5)
                const int r = tA*4 + qA;
                if (k < 2)      v = Wih0[r*2 + k];
                else if (k < 6) v = Whh0[r*4 + (k-2)];
            } else {                              // L1 rows: h0(k2-5), h1(k6-9)
                const int r = tA*4 + (qA-4);
                if (k >= 2 && k < 6)       v = Wih1[r*4 + (k-2)];
                else if (k >= 6 && k < 10) v = Whh1[r*4 + (k-6)];
            }
            vv[z] = v * sA;
        }
        au[p] = PKU(vv[0], vv[1]);
    }
    const fp16x8 Afrag = __builtin_bit_cast(fp16x8, au);

    // ---- bias as C operand (loop-invariant) ----
    f32x16 biasC;
#pragma unroll
    for (int r = 0; r < 16; ++r){
        const int m = (r&3) + 8*(r>>2) + 4*h;
        const int q = m >> 2, tg = m & 3;
        const float st = (tg == 2) ? S2 : S1;
        if (q < 4){ const int rr = tg*4 + q;      biasC[r] = (bih0[rr]+bhh0[rr])*st; }
        else      { const int rr = tg*4 + (q-4);  biasC[r] = (bih1[rr]+bhh1[rr])*st; }
    }

    float c0l=0.f, c0h=0.f, c1l=0.f, c1h=0.f, acc=0.f;
    unsigned pk_h0_01=0u, pk_h0_23=0u, pk_h1_01=0u, pk_h1_23=0u;

    const float* xg = x + (size_t)E0 * (T_LEN*2);

    // ---- stage chunk0 (t=0..23): coalesced dwordx4, 6 per lane ----
    float4 rb[6];
#pragma unroll
    for (int k = 0; k < 6; ++k){
        const int i = 64*k + lane, e_ = i/12, c_ = i%12;
        rb[k] = *reinterpret_cast<const float4*>(xg + e_*100 + c_*4);
    }
#pragma unroll
    for (int k = 0; k < 6; ++k){
        const int i = 64*k + lane, e_ = i/12, c_ = i%12;
        float* p = xr + e_*RS + c_*4;
        *reinterpret_cast<float2*>(p)     = make_float2(rb[k].x, rb[k].y);
        *reinterpret_cast<float2*>(p + 2) = make_float2(rb[k].z, rb[k].w);
    }
    // ---- prefetch chunk1 (t=24..47) + tail (t=48..49) into registers ----
#pragma unroll
    for (int k = 0; k < 6; ++k){
        const int i = 64*k + lane, e_ = i/12, c_ = i%12;
        rb[k] = *reinterpret_cast<const float4*>(xg + e_*100 + 48 + c_*4);
    }
    float4 rt;
    if (lane < 32) rt = *reinterpret_cast<const float4*>(xg + lane*100 + 96);

    // one full step: L0(t) + L1(t-1) via one MFMA, then 4 lane-local acts
    auto mainstep = [&](int t, float2 xv){
        const unsigned ux = PKU(xv.x, xv.y);
        uint4v bu;
        bu[0] = h ? pk_h1_23 : ux;
        bu[1] = pk_h0_01;
        bu[2] = pk_h0_23;
        bu[3] = pk_h1_01;
        const f32x16 d = __builtin_amdgcn_mfma_f32_32x32x16_f16(
            Afrag, __builtin_bit_cast(fp16x8, bu), biasC, 0, 0, 0);
        float h0l,h0h,h1l,h1h;
        act(d[0], d[1], d[2], d[3],  c0l, h0l);
        act(d[4], d[5], d[6], d[7],  c0h, h0h);
        act(d[8], d[9], d[10],d[11], c1l, h1l);
        act(d[12],d[13],d[14],d[15], c1h, h1h);
        const float2 wo = wout_s[(t-1)*2 + h];
        acc = fmaf(h1l, wo.x, fmaf(h1h, wo.y, acc));
        const float r0l = __shfl_xor(h0l,32,64), r0h = __shfl_xor(h0h,32,64);
        const float r1l = __shfl_xor(h1l,32,64), r1h = __shfl_xor(h1h,32,64);
        pk_h0_01 = PKU(h0l, r0l);
        pk_h0_23 = PKU(h0h, r0h);
        pk_h1_01 = PKU(h1l, r1l);
        pk_h1_23 = PKU(r1h, h1h);
    };

    // ---- prologue t=0: L0 only ----
    {
        const float2 xv = *reinterpret_cast<const float2*>(xr + e*RS);
        const unsigned ux = PKU(xv.x, xv.y);
        uint4v bu; bu[0] = h ? 0u : ux; bu[1] = 0u; bu[2] = 0u; bu[3] = 0u;
        const f32x16 d = __builtin_amdgcn_mfma_f32_32x32x16_f16(
            Afrag, __builtin_bit_cast(fp16x8, bu), biasC, 0, 0, 0);
        float h0l, h0h;
        act(d[0],d[1],d[2],d[3], c0l, h0l);
        act(d[4],d[5],d[6],d[7], c0h, h0h);
        const float r0l = __shfl_xor(h0l, 32, 64);
        const float r0h = __shfl_xor(h0h, 32, 64);
        pk_h0_01 = PKU(h0l, r0l);
        pk_h0_23 = PKU(h0h, r0h);
    }

    for (int t = 1; t < 24; ++t)
        mainstep(t, *reinterpret_cast<const float2*>(xr + e*RS + 2*t));

    // write chunk1 (reads of chunk0 already issued; DS is in-order per wave)
#pragma unroll
    for (int k = 0; k < 6; ++k){
        const int i = 64*k + lane, e_ = i/12, c_ = i%12;
        float* p = xr + e_*RS + c_*4;
        *reinterpret_cast<float2*>(p)     = make_float2(rb[k].x, rb[k].y);
        *reinterpret_cast<float2*>(p + 2) = make_float2(rb[k].z, rb[k].w);
    }
    for (int t = 24; t < 48; ++t)
        mainstep(t, *reinterpret_cast<const float2*>(xr + e*RS + 2*(t-24)));

    // write tail (t=48,49)
    if (lane < 32){
        float* p = xr + lane*RS;
        *reinterpret_cast<float2*>(p)     = make_float2(rt.x, rt.y);
        *reinterpret_cast<float2*>(p + 2) = make_float2(rt.z, rt.w);
    }
    for (int t = 48; t < 50; ++t)
        mainstep(t, *reinterpret_cast<const float2*>(xr + e*RS + 2*(t-48)));

    // ---- epilogue: L1 at t=49 ----
    {
        uint4v bu;
        bu[0] = h ? pk_h1_23 : 0u;
        bu[1] = pk_h0_01; bu[2] = pk_h0_23; bu[3] = pk_h1_01;
        const f32x16 d = __builtin_amdgcn_mfma_f32_32x32x16_f16(
            Afrag, __builtin_bit_cast(fp16x8, bu), biasC, 0, 0, 0);
        float h1l, h1h;
        act(d[8], d[9], d[10],d[11], c1l, h1l);
        act(d[12],d[13],d[14],d[15], c1h, h1h);
        const float2 wo = wout_s[49*2 + h];
        acc = fmaf(h1l, wo.x, fmaf(h1h, wo.y, acc));
    }

    acc += __shfl_xor(acc, 32, 64);
    if (h == 0){
        const float z = acc + bout[0];
        out[E0 + e] = RCP(1.0f + EXP2(z * S1));   // sigmoid
    }
}

extern "C" void kernel_launch(void* const* d_in, const int* in_sizes, int n_in,
                              void* d_out, int out_size, void* d_ws, size_t ws_size,
                              hipStream_t stream)
{
    const float* x    = (const float*)d_in[0];
    const float* Wih0 = (const float*)d_in[1];
    const float* Whh0 = (const float*)d_in[2];
    const float* bih0 = (const float*)d_in[3];
    const float* bhh0 = (const float*)d_in[4];
    const float* Wih1 = (const float*)d_in[5];
    const float* Whh1 = (const float*)d_in[6];
    const float* bih1 = (const float*)d_in[7];
    const float* bhh1 = (const float*)d_in[8];
    const float* Wout = (const float*)d_in[9];
    const float* bout = (const float*)d_in[10];
    float* out = (float*)d_out;

    const int B = in_sizes[0] / (T_LEN*2);
    const int waves = (B + 31) / 32;
    const int blocks = (waves + 3) / 4;       // 4 waves per 256-thread block
    lstm_mfma32<<<blocks, 256, 0, stream>>>(x, Wih0, Whh0, bih0, bhh0,
                                            Wih1, Whh1, bih1, bhh1,
                                            Wout, bout, out, B);
}